// Round 4
// baseline (291.761 us; speedup 1.0000x reference)
//
#include <hip/hip_runtime.h>

// Problem constants (from reference setup_inputs) — all tensors are float32.
#define B_DIM 2
#define C_DIM 64
#define N_DIM 1024
#define E_DIM 32
#define BE_DIM (B_DIM * E_DIM)   // 64
#define ITILE 16                 // rows of the N x N image per block

// 1/ln2 and 2/ln2 — fold sigmoid's exp into native exp2 (v_exp_f32).
#define RCP_LN2     1.4426950408889634f
#define TWO_RCP_LN2 2.8853900817779268f

// Native clang vector type (required by __builtin_nontemporal_store; also
// gives scalar-splat arithmetic for the dot-product accumulators).
typedef float f32x4 __attribute__((ext_vector_type(4)));

// ---------------------------------------------------------------------------
// FUSED kernel (round 4): one dispatch does everything.
//
//   t1[j] = sum_c th12_1[e,c]*emb[b,c,j]   (ditto t2 with th12_2)
//   out[b,e,i,j] = relu(2*max(t1i,t1j) + th5_1[e]*(i==j))
//                * sigmoid(relu(2*max(t2i,t2j) + th5_2[e]*(i==j)))
//
// Rationale (fixed-poison model, R0-R3): our controllable region is ~65 µs
// vs a ~50 µs floor; the removable pieces are the compute_t dispatch, the
// inter-kernel gap, and the t round-trip. Each block recomputes its own
// t-slices from emb (512 KB, L2-resident): per thread one 64-c dot product
// for its 4 j's (~7 µs chip-wide VALU, hidden under the ~41 µs store drain;
// ~1 GiB of L2 reads ≈ 30 µs at 34.5 TB/s, disjoint from the nt-store HBM
// path). The 16 row-scalars t[i0..i0+15] are already computed by the 4
// threads owning j∈[i0,i0+16) — published via 128 B of LDS, one barrier.
//
// Kept from R3: nt f32x4 stores (write-once 268 MB output), sigmoid folded
// onto native exp2 (2/ln2 pre-scale; relu commutes with positive scale),
// diagonal fixup outside the hot loop (t[i]==t[j] there).
// ---------------------------------------------------------------------------
__global__ __launch_bounds__(256) void fused_kernel(
    const float* __restrict__ emb,
    const float* __restrict__ th12_1,
    const float* __restrict__ th12_2,
    const float* __restrict__ th5_1,
    const float* __restrict__ th5_2,
    float* __restrict__ out)
{
    const int be = blockIdx.y;
    const int b  = be >> 5;       // E=32
    const int e  = be & (E_DIM - 1);
    const int i0 = blockIdx.x * ITILE;
    const int jb = threadIdx.x * 4;

    // ---- per-thread t-slices: two 64-c dot products for j = jb..jb+3 ----
    const float* __restrict__ embp = emb + (size_t)b * C_DIM * N_DIM + jb;
    const float* __restrict__ w1   = th12_1 + e * C_DIM;   // block-uniform
    const float* __restrict__ w2   = th12_2 + e * C_DIM;

    f32x4 acc1 = {0.f, 0.f, 0.f, 0.f};
    f32x4 acc2 = {0.f, 0.f, 0.f, 0.f};
#pragma unroll 16
    for (int c = 0; c < C_DIM; ++c) {
        const f32x4 x = *reinterpret_cast<const f32x4*>(embp + (size_t)c * N_DIM);
        acc1 += w1[c] * x;
        acc2 += w2[c] * x;
    }

    // adj side: 2*t1[j].  gate side: (2/ln2)*t2[j].
    const f32x4 a2 = acc1 + acc1;
    const f32x4 gs = acc2 * TWO_RCP_LN2;

    // ---- publish the block's 16 row-scalars (threads owning j==i rows) ----
    __shared__ float t1i2_lds[ITILE];   // 2*t1[i]
    __shared__ float t2is_lds[ITILE];   // (2/ln2)*t2[i]
    const int rel = jb - i0;            // in {0,4,8,12} for 4 threads
    if ((unsigned)rel < (unsigned)ITILE) {
#pragma unroll
        for (int k = 0; k < 4; ++k) {
            t1i2_lds[rel + k] = a2[k];
            t2is_lds[rel + k] = gs[k];
        }
    }
    __syncthreads();

    float t1i2[ITILE], t2is[ITILE];
#pragma unroll
    for (int r = 0; r < ITILE; ++r) {   // same-address LDS reads: broadcast
        t1i2[r] = t1i2_lds[r];
        t2is[r] = t2is_lds[r];
    }

    const float th51  = th5_1[e];
    const float th52s = th5_2[e] * RCP_LN2;   // scaled diagonal term (gate)

    // ---- emit 16 rows ----
    float* dst = out + ((size_t)be * N_DIM + i0) * N_DIM + jb;

#pragma unroll
    for (int r = 0; r < ITILE; ++r) {
        const int i = i0 + r;

        f32x4 o;
#pragma unroll
        for (int k = 0; k < 4; ++k) {
            const float adj  = fmaxf(fmaxf(t1i2[r], a2[k]), 0.f);
            const float y    = fmaxf(fmaxf(t2is[r], gs[k]), 0.f);
            const float gate = __builtin_amdgcn_rcpf(1.f + exp2f(-y));
            o[k] = adj * gate;
        }

        // Diagonal: j == i falls in this thread's 4-wide range for exactly
        // one thread per row; there max(t[i],t[j]) == t[i].
        const int kd = i - jb;
        if ((unsigned)kd < 4u) {
            const float adjd = fmaxf(t1i2[r] + th51, 0.f);
            const float yd   = fmaxf(t2is[r] + th52s, 0.f);
            o[kd] = adjd * __builtin_amdgcn_rcpf(1.f + exp2f(-yd));
        }

        __builtin_nontemporal_store(o,
            reinterpret_cast<f32x4*>(dst + (size_t)r * N_DIM));
    }
}

// ---------------------------------------------------------------------------
extern "C" void kernel_launch(void* const* d_in, const int* in_sizes, int n_in,
                              void* d_out, int out_size, void* d_ws, size_t ws_size,
                              hipStream_t stream) {
    const float* emb    = (const float*)d_in[0];
    const float* th12_1 = (const float*)d_in[1];
    // d_in[2] = th34_1 (unused by reference)
    const float* th5_1  = (const float*)d_in[3];
    const float* th12_2 = (const float*)d_in[4];
    // d_in[5] = th34_2 (unused by reference)
    const float* th5_2  = (const float*)d_in[6];
    float* out = (float*)d_out;
    (void)d_ws; (void)ws_size;   // workspace no longer used

    dim3 g(N_DIM / ITILE, BE_DIM);
    fused_kernel<<<g, 256, 0, stream>>>(emb, th12_1, th12_2, th5_1, th5_2, out);
}

// Round 5
// 268.511 us; speedup vs baseline: 1.0866x; 1.0866x over previous
//
#include <hip/hip_runtime.h>

// Problem constants (from reference setup_inputs) — all tensors are float32.
#define B_DIM 2
#define C_DIM 64
#define N_DIM 1024
#define E_DIM 32
#define BE_DIM (B_DIM * E_DIM)   // 64

// ---------------------------------------------------------------------------
// REVERT (round 5): exact resubmission of the round-0 kernel — the best
// measurement on record (267.8 µs; fill-adjusted our-region ~65 µs).
// Rounds 1-4 established: row-tiling (null), nt-stores + exp2-folded sigmoid
// (null), full fusion (negative, +9 µs — per-block emb re-read + prologue
// barrier thins the store pipe). The edge kernel's ~55-60 µs sits ~15 µs
// above the pure-write floor (41 µs at the harness fill kernel's own
// 6.6 TB/s), and that residual has resisted three orthogonal attacks —
// it is launch ramp + t-row L2 reads, not recoverable at source level.
// ---------------------------------------------------------------------------

// Kernel 1: t[b,e,n] = sum_c th12[e,c] * emb[b,c,n], for both parameter sets.
// Grid: (N/256, BE), block 256. ~17 MFLOP total — negligible.
__global__ __launch_bounds__(256) void compute_t_kernel(
    const float* __restrict__ emb,
    const float* __restrict__ th12_1,
    const float* __restrict__ th12_2,
    float* __restrict__ t1,
    float* __restrict__ t2)
{
    const int n  = blockIdx.x * 256 + threadIdx.x;
    const int be = blockIdx.y;
    const int b  = be >> 5;       // E=32
    const int e  = be & 31;

    const float* __restrict__ embp = emb + (size_t)b * C_DIM * N_DIM + n;
    const float* __restrict__ w1   = th12_1 + e * C_DIM;
    const float* __restrict__ w2   = th12_2 + e * C_DIM;

    float acc1 = 0.f, acc2 = 0.f;
#pragma unroll
    for (int c = 0; c < C_DIM; ++c) {
        const float x = embp[(size_t)c * N_DIM];
        acc1 = fmaf(w1[c], x, acc1);
        acc2 = fmaf(w2[c], x, acc2);
    }
    t1[be * N_DIM + n] = acc1;
    t2[be * N_DIM + n] = acc2;
}

// Kernel 2: out[b,e,i,j] = relu(2*max(t1i,t1j) + th5_1[e]*(i==j))
//                        * sigmoid(relu(2*max(t2i,t2j) + th5_2[e]*(i==j)))
// Grid: (N, BE), block 256. One row i per block; each lane produces 4
// consecutive j -> one float4 (16 B) coalesced store per lane.
__global__ __launch_bounds__(256) void edge_kernel(
    const float* __restrict__ t1,
    const float* __restrict__ t2,
    const float* __restrict__ th5_1,
    const float* __restrict__ th5_2,
    float* __restrict__ out)
{
    const int be = blockIdx.y;
    const int e  = be & 31;
    const int i  = blockIdx.x;
    const int jb = threadIdx.x * 4;

    const float* __restrict__ t1r = t1 + be * N_DIM;
    const float* __restrict__ t2r = t2 + be * N_DIM;

    const float t1i  = t1r[i];
    const float t2i  = t2r[i];
    const float th51 = th5_1[e];
    const float th52 = th5_2[e];

    const float4 a = *reinterpret_cast<const float4*>(t1r + jb);
    const float4 g = *reinterpret_cast<const float4*>(t2r + jb);

    const float v1[4] = {a.x, a.y, a.z, a.w};
    const float v2[4] = {g.x, g.y, g.z, g.w};

    float4 o;
    float* op = reinterpret_cast<float*>(&o);
#pragma unroll
    for (int k = 0; k < 4; ++k) {
        float d1 = 2.f * fmaxf(t1i, v1[k]);
        float d2 = 2.f * fmaxf(t2i, v2[k]);
        if (i == jb + k) { d1 += th51; d2 += th52; }   // diagonal term
        const float adj  = fmaxf(d1, 0.f);
        const float rg   = fmaxf(d2, 0.f);
        const float gate = 1.f / (1.f + __expf(-rg));
        op[k] = adj * gate;
    }

    float* dst = out + ((size_t)be * N_DIM + i) * N_DIM + jb;
    *reinterpret_cast<float4*>(dst) = o;
}

// ---------------------------------------------------------------------------
extern "C" void kernel_launch(void* const* d_in, const int* in_sizes, int n_in,
                              void* d_out, int out_size, void* d_ws, size_t ws_size,
                              hipStream_t stream) {
    const float* emb    = (const float*)d_in[0];
    const float* th12_1 = (const float*)d_in[1];
    // d_in[2] = th34_1 (unused by reference)
    const float* th5_1  = (const float*)d_in[3];
    const float* th12_2 = (const float*)d_in[4];
    // d_in[5] = th34_2 (unused by reference)
    const float* th5_2  = (const float*)d_in[6];
    float* out = (float*)d_out;

    float* t1 = (float*)d_ws;                       // BE*N floats = 256 KB
    float* t2 = t1 + (size_t)BE_DIM * N_DIM;        // another 256 KB

    dim3 g1(N_DIM / 256, BE_DIM);
    compute_t_kernel<<<g1, 256, 0, stream>>>(emb, th12_1, th12_2, t1, t2);

    dim3 g2(N_DIM, BE_DIM);
    edge_kernel<<<g2, 256, 0, stream>>>(t1, t2, th5_1, th5_2, out);
}